// Round 2
// baseline (924.940 us; speedup 1.0000x reference)
//
#include <hip/hip_runtime.h>

// QuantLinear: y[t,o] = (sum_k x[t,k] * (q[o,k]-8)) * scale[o] + bias[o]
// Scale factored out of K-reduction -> bf16 MFMA GEMM on (q-8), epilogue scale/bias.
// 256x256x64 8-phase pipelined GEMM (guide §5 template):
//   - 8 waves (2Mx4N), 512 threads, per-wave 128x64 output, acc[8][4] f32x4
//   - LDS 128 KiB: 2 dbuf x (A 256x64 + B 256x64) bf16
//   - ROUND 2 FIX: bank swizzle now XORs chunk-bit-2 (64B) with row-bit-2
//     (byte ^= ((byte>>9)&1)<<6). Fragment reads then spread 64 lanes over all
//     8 k-chunk slots = all 32 banks, 8 words/bank = conflict-free (was 2x:
//     old bit-1 swizzle kept reads in banks 0-15 -> 4.4e7 SQ_LDS_BANK_CONFLICT).
//   - explicit lgkmcnt asm removed: reads are compiler-visible; hipcc emits
//     minimal counted lgkmcnt before each dependent MFMA (guide §5/G7).
//   - 4 phases per K-tile: quadrants (m0-3/m4-7 x n0-1/n2-3) over K=64;
//     all LDS reads of a tile done by phase 2 -> phase 3/4 may stage into same buffer
//   - 1 half-tile (2x global_load_lds width-16) staged per phase; vmcnt(4) once
//     per K-tile (counted, never 0 until the final pair); s_setprio around MFMA
//   - bijective XCD swizzle over the 896-block grid (896 % 8 == 0)

#define AS1 __attribute__((address_space(1)))
#define AS3 __attribute__((address_space(3)))

typedef __attribute__((ext_vector_type(8))) short short8;
typedef __attribute__((ext_vector_type(4))) float f32x4;

static constexpr int IN_F   = 4096;    // K
static constexpr int OUT_F  = 14336;   // N
static constexpr int TOKENS = 4096;    // M

// ---------------- fused conversion kernel (grid-stride) ----------------

__device__ __forceinline__ unsigned short bf16_rne(float f) {
    unsigned int u = __float_as_uint(f);
    u += 0x7fffu + ((u >> 16) & 1u);
    return (unsigned short)(u >> 16);
}

__global__ void convert_kernel(const int4* __restrict__ q, ushort4* __restrict__ wb,
                               const float4* __restrict__ x, ushort4* __restrict__ xb) {
    constexpr size_t NW = (size_t)OUT_F * IN_F / 4;    // 14,680,064 int4-groups
    constexpr size_t NX = (size_t)TOKENS * IN_F / 4;   //  4,194,304 float4-groups
    const size_t stride = (size_t)gridDim.x * blockDim.x;
    for (size_t i = (size_t)blockIdx.x * blockDim.x + threadIdx.x; i < NW + NX;
         i += stride) {
        if (i < NW) {
            int4 v = q[i];
            ushort4 r;  // small ints exact in bf16: truncate fp32 bits
            r.x = (unsigned short)(__float_as_uint((float)(v.x - 8)) >> 16);
            r.y = (unsigned short)(__float_as_uint((float)(v.y - 8)) >> 16);
            r.z = (unsigned short)(__float_as_uint((float)(v.z - 8)) >> 16);
            r.w = (unsigned short)(__float_as_uint((float)(v.w - 8)) >> 16);
            wb[i] = r;
        } else {
            size_t j = i - NW;
            float4 v = x[j];
            ushort4 r;
            r.x = bf16_rne(v.x); r.y = bf16_rne(v.y);
            r.z = bf16_rne(v.z); r.w = bf16_rne(v.w);
            xb[j] = r;
        }
    }
}

// ---------------- 256x256x64 8-phase GEMM: C = A * B^T ----------------

#define STAGE(T_, Q_, MATP_)                                                               \
    do {                                                                                   \
        const unsigned short* g_ = ((Q_) < 2 ? gA : gB) + ((Q_) & 1) * (size_t)(128 * K)   \
                                   + (size_t)(T_) * BK;                                    \
        unsigned short* l_ = (MATP_) + ((Q_) & 1) * HS + tid * 8;                          \
        __builtin_amdgcn_global_load_lds((const AS1 void*)g_, (AS3 void*)l_, 16, 0, 0);    \
        __builtin_amdgcn_global_load_lds((const AS1 void*)(g_ + (size_t)64 * K),           \
                                         (AS3 void*)(l_ + 4096), 16, 0, 0);                \
    } while (0)

#define BAR()                                                                              \
    do {                                                                                   \
        asm volatile("" ::: "memory");                                                     \
        __builtin_amdgcn_s_barrier();                                                      \
        asm volatile("" ::: "memory");                                                     \
    } while (0)

#define MFMA_QUAD(M0_, N0_)                                                                \
    __builtin_amdgcn_s_setprio(1);                                                         \
    _Pragma("unroll") for (int s_ = 0; s_ < 2; ++s_)                                       \
        _Pragma("unroll") for (int m_ = 0; m_ < 4; ++m_)                                   \
            _Pragma("unroll") for (int n_ = 0; n_ < 2; ++n_)                               \
                acc[(M0_) + m_][(N0_) + n_] = __builtin_amdgcn_mfma_f32_16x16x32_bf16(     \
                    af[(M0_) + m_][s_], bf[(N0_) + n_][s_],                                \
                    acc[(M0_) + m_][(N0_) + n_], 0, 0, 0);                                 \
    __builtin_amdgcn_s_setprio(0);

// One K-tile = 4 phases. TA_/TB_: current buffers. NXA_: A of SAME buffer
// (receives tile T+2, safe from phase 3: all reads of tile T finish in phase 2).
// NXB_: B of OTHER buffer (receives tile T+1).
// Fragment s=0 of global k-chunk lq lives at LDS chunk klane; s=1 (k-chunk lq+4)
// at klane^4 -> byte offset XOR 64 == short offset XOR 32 (no carry: row field
// starts at bit 6 of the short offset).
#define KTILE(T_, TA_, TB_, NXA_, NXB_)                                                    \
    do {                                                                                   \
        /* --- phase 1: read A m0-3 + B n0-1 (both k-steps); quad (m0-3 x n0-1) --- */     \
        _Pragma("unroll") for (int m_ = 0; m_ < 4; ++m_) {                                 \
            af[m_][0] = *(const short8*)((TA_) + aOff  + m_ * 1024);                       \
            af[m_][1] = *(const short8*)((TA_) + aOffB + m_ * 1024);                       \
        }                                                                                  \
        _Pragma("unroll") for (int n_ = 0; n_ < 2; ++n_) {                                 \
            bf[n_][0] = *(const short8*)((TB_) + bOff  + n_ * 1024);                       \
            bf[n_][1] = *(const short8*)((TB_) + bOffB + n_ * 1024);                       \
        }                                                                                  \
        if ((T_) + 1 < NT) STAGE((T_) + 1, 2, NXB_);                                       \
        BAR();                                                                             \
        MFMA_QUAD(0, 0)                                                                    \
        BAR();                                                                             \
        /* --- phase 2: read A m4-7 (needed now) + B n2-3 (needed ph3) --- */              \
        _Pragma("unroll") for (int m_ = 0; m_ < 4; ++m_) {                                 \
            af[4 + m_][0] = *(const short8*)((TA_) + aOff  + (4 + m_) * 1024);             \
            af[4 + m_][1] = *(const short8*)((TA_) + aOffB + (4 + m_) * 1024);             \
        }                                                                                  \
        _Pragma("unroll") for (int n_ = 0; n_ < 2; ++n_) {                                 \
            bf[2 + n_][0] = *(const short8*)((TB_) + bOff  + (2 + n_) * 1024);             \
            bf[2 + n_][1] = *(const short8*)((TB_) + bOffB + (2 + n_) * 1024);             \
        }                                                                                  \
        if ((T_) + 1 < NT) STAGE((T_) + 1, 3, NXB_);                                       \
        BAR();                                                                             \
        MFMA_QUAD(4, 0)                                                                    \
        BAR();                                                                             \
        /* --- phase 3: no reads; quad (m0-3 x n2-3) --- */                                \
        if ((T_) + 2 < NT) STAGE((T_) + 2, 0, NXA_);                                       \
        BAR();                                                                             \
        MFMA_QUAD(0, 2)                                                                    \
        BAR();                                                                             \
        /* --- phase 4: no reads; quad (m4-7 x n2-3); counted vmcnt --- */                 \
        if ((T_) + 2 < NT) STAGE((T_) + 2, 1, NXA_);                                       \
        BAR();                                                                             \
        MFMA_QUAD(4, 2)                                                                    \
        if ((T_) + 2 < NT) {                                                               \
            asm volatile("s_waitcnt vmcnt(4)" ::: "memory");                               \
        } else {                                                                           \
            asm volatile("s_waitcnt vmcnt(0)" ::: "memory");                               \
        }                                                                                  \
        BAR();                                                                             \
    } while (0)

__global__ __launch_bounds__(512, 2)
void gemm256_kernel(const unsigned short* __restrict__ A,   // bf16 [M,K]
                    const unsigned short* __restrict__ B,   // bf16 [N,K]
                    const float* __restrict__ scale,        // [N]
                    const float* __restrict__ bias,         // [N]
                    float* __restrict__ C) {                // [M,N]
    constexpr int K  = IN_F;
    constexpr int N  = OUT_F;
    constexpr int BK = 64;
    constexpr int NT = K / BK;        // 64 K-tiles
    constexpr int TS = 256 * BK;      // shorts per tile (16384 = 32 KiB)
    constexpr int HS = TS / 2;        // shorts per 128-row half

    __shared__ unsigned short sm[2][2][TS];   // [buf][A|B][256*64] = 128 KiB

    const int tid  = threadIdx.x;
    const int lane = tid & 63;
    const int wave = tid >> 6;
    const int l16  = lane & 15;
    const int lq   = lane >> 4;
    const int wr   = wave >> 2;       // 0..1  (M position)
    const int wc   = wave & 3;        // 0..3  (N position)

    // bijective XCD swizzle: 896 tiles, each XCD gets 112 contiguous logical
    // tiles = 2 full M-rows -> A panel (4 MB) fits that XCD's L2.
    const int bid   = blockIdx.y * 56 + blockIdx.x;
    const int swz   = (bid & 7) * 112 + (bid >> 3);
    const int nBase = (swz % 56) * 256;
    const int mBase = (swz / 56) * 256;

    // staging: LDS chunk c (16B) holds global chunk c ^ (((c>>5)&1)<<2):
    // XOR chunk-bit-2 (64B granule) with row-bit-2 (c bit 5). Involution; row
    // (c>>3) unchanged; global footprint per row unchanged (64B halves swap).
    const int cs   = tid ^ (((tid >> 5) & 1) << 2);
    const int srow = tid >> 3;         // 0..63 (row unaffected by the XOR)
    const int scol = (cs & 7) * 8;     // shorts within row
    const unsigned short* gA = A + (size_t)(mBase + srow) * K + scol;
    const unsigned short* gB = B + (size_t)(nBase + srow) * K + scol;

    // swizzled reader: lane (l16,lq) finds global k-chunk lq at LDS chunk
    // lq ^ (((l16>>2)&1)<<2); k-chunk lq+4 at (that)^4.
    const int klane = lq ^ (((l16 >> 2) & 1) << 2);
    const int aOff  = (wr * 128 + l16) * 64 + klane * 8;
    const int bOff  = (wc * 64  + l16) * 64 + klane * 8;
    const int aOffB = aOff ^ 32;       // chunk klane^4
    const int bOffB = bOff ^ 32;

    f32x4  acc[8][4] = {};
    short8 af[8][2];
    short8 bf[4][2];

    unsigned short* smA0 = &sm[0][0][0];
    unsigned short* smB0 = &sm[0][1][0];
    unsigned short* smA1 = &sm[1][0][0];
    unsigned short* smB1 = &sm[1][1][0];

    // prologue: tile0 {A0,A1,B0,B1} + tile1 {A0,A1}; drain tile0, keep 4 in flight
    STAGE(0, 0, smA0); STAGE(0, 1, smA0); STAGE(0, 2, smB0); STAGE(0, 3, smB0);
    STAGE(1, 0, smA1); STAGE(1, 1, smA1);
    asm volatile("s_waitcnt vmcnt(4)" ::: "memory");
    BAR();

    for (int t = 0; t < NT; t += 2) {
        KTILE(t,     smA0, smB0, smA0, smB1);
        KTILE(t + 1, smA1, smB1, smA1, smB0);
    }

    // epilogue: C/D layout col = lane&15 (n side), row = (lane>>4)*4 + reg (m side)
#pragma unroll
    for (int n = 0; n < 4; ++n) {
        const int col  = nBase + wc * 64 + n * 16 + l16;
        const float s  = scale[col];
        const float bb = bias[col];
#pragma unroll
        for (int m = 0; m < 8; ++m) {
            const int row0 = mBase + wr * 128 + m * 16 + lq * 4;
            float* cp = C + (size_t)row0 * N + col;
#pragma unroll
            for (int r = 0; r < 4; ++r)
                cp[(size_t)r * N] = acc[m][n][r] * s + bb;
        }
    }
}

// ---------------- launch ----------------

extern "C" void kernel_launch(void* const* d_in, const int* in_sizes, int n_in,
                              void* d_out, int out_size, void* d_ws, size_t ws_size,
                              hipStream_t stream) {
    const float* x      = (const float*)d_in[0];  // [2,2048,4096] fp32
    const int*   wq     = (const int*)d_in[1];    // [14336,4096] int32 in [0,16)
    const float* wscale = (const float*)d_in[2];  // [14336,1]
    const float* wbias  = (const float*)d_in[3];  // [14336]
    float* out = (float*)d_out;                   // [2,2048,14336] fp32

    unsigned short* wbf = (unsigned short*)d_ws;                    // 117.4 MB
    unsigned short* xbf = wbf + (size_t)OUT_F * IN_F;               // +33.6 MB

    convert_kernel<<<2048, 256, 0, stream>>>((const int4*)wq, (ushort4*)wbf,
                                             (const float4*)x, (ushort4*)xbf);

    gemm256_kernel<<<dim3(56, 16), 512, 0, stream>>>(xbf, wbf, wscale, wbias, out);
}

// Round 3
// 869.439 us; speedup vs baseline: 1.0638x; 1.0638x over previous
//
#include <hip/hip_runtime.h>

// QuantLinear: y[t,o] = (sum_k x[t,k] * (q[o,k]-8)) * scale[o] + bias[o]
// Scale factored out of K-reduction -> bf16 MFMA GEMM on (q-8), epilogue scale/bias.
// 256x256x64 8-phase pipelined GEMM (guide §5 template):
//   - 8 waves (2Mx4N), 512 threads, per-wave 128x64 output, acc[8][4] f32x4
//   - LDS 128 KiB: 2 dbuf x (A 256x64 + B 256x64) bf16
//   - ROUND 3 FIX: FULL 3-bit bank swizzle (G4): LDS 16B-chunk position p of
//     row r holds global k-chunk p ^ (r & 7)  (byte ^= (row&7)<<4).
//     Fragment reads then put every 8 consecutive lanes on 8 distinct 16B
//     slots = all 32 banks. Rounds 1/2 used 1-bit XORs -> every 8-lane group
//     hit only 2 slots = 4-way conflict (SQ_LDS_BANK_CONFLICT identical 4.4e7
//     across both variants; 43k reads/CU x 32 bank-cyc == measured kernel
//     cycles, i.e. 100% LDS-serialized).
//   - 4 phases per K-tile: quadrants (m0-3/m4-7 x n0-1/n2-3) over K=64;
//     all LDS reads of a tile done by phase 2 -> phase 3/4 may stage into same buffer
//   - 1 half-tile (2x global_load_lds width-16) staged per phase; vmcnt(4) once
//     per K-tile (counted, never 0 until the final pair); s_setprio around MFMA
//   - bijective XCD swizzle over the 896-block grid (896 % 8 == 0)

#define AS1 __attribute__((address_space(1)))
#define AS3 __attribute__((address_space(3)))

typedef __attribute__((ext_vector_type(8))) short short8;
typedef __attribute__((ext_vector_type(4))) float f32x4;

static constexpr int IN_F   = 4096;    // K
static constexpr int OUT_F  = 14336;   // N
static constexpr int TOKENS = 4096;    // M

// ---------------- fused conversion kernel (grid-stride) ----------------

__device__ __forceinline__ unsigned short bf16_rne(float f) {
    unsigned int u = __float_as_uint(f);
    u += 0x7fffu + ((u >> 16) & 1u);
    return (unsigned short)(u >> 16);
}

__global__ void convert_kernel(const int4* __restrict__ q, ushort4* __restrict__ wb,
                               const float4* __restrict__ x, ushort4* __restrict__ xb) {
    constexpr size_t NW = (size_t)OUT_F * IN_F / 4;    // 14,680,064 int4-groups
    constexpr size_t NX = (size_t)TOKENS * IN_F / 4;   //  4,194,304 float4-groups
    const size_t stride = (size_t)gridDim.x * blockDim.x;
    for (size_t i = (size_t)blockIdx.x * blockDim.x + threadIdx.x; i < NW + NX;
         i += stride) {
        if (i < NW) {
            int4 v = q[i];
            ushort4 r;  // small ints exact in bf16: truncate fp32 bits
            r.x = (unsigned short)(__float_as_uint((float)(v.x - 8)) >> 16);
            r.y = (unsigned short)(__float_as_uint((float)(v.y - 8)) >> 16);
            r.z = (unsigned short)(__float_as_uint((float)(v.z - 8)) >> 16);
            r.w = (unsigned short)(__float_as_uint((float)(v.w - 8)) >> 16);
            wb[i] = r;
        } else {
            size_t j = i - NW;
            float4 v = x[j];
            ushort4 r;
            r.x = bf16_rne(v.x); r.y = bf16_rne(v.y);
            r.z = bf16_rne(v.z); r.w = bf16_rne(v.w);
            xb[j] = r;
        }
    }
}

// ---------------- 256x256x64 8-phase GEMM: C = A * B^T ----------------

#define STAGE(T_, Q_, MATP_)                                                               \
    do {                                                                                   \
        const unsigned short* g_ = ((Q_) < 2 ? gA : gB) + ((Q_) & 1) * (size_t)(128 * K)   \
                                   + (size_t)(T_) * BK;                                    \
        unsigned short* l_ = (MATP_) + ((Q_) & 1) * HS + tid * 8;                          \
        __builtin_amdgcn_global_load_lds((const AS1 void*)g_, (AS3 void*)l_, 16, 0, 0);    \
        __builtin_amdgcn_global_load_lds((const AS1 void*)(g_ + (size_t)64 * K),           \
                                         (AS3 void*)(l_ + 4096), 16, 0, 0);                \
    } while (0)

#define BAR()                                                                              \
    do {                                                                                   \
        asm volatile("" ::: "memory");                                                     \
        __builtin_amdgcn_s_barrier();                                                      \
        asm volatile("" ::: "memory");                                                     \
    } while (0)

#define MFMA_QUAD(M0_, N0_)                                                                \
    __builtin_amdgcn_s_setprio(1);                                                         \
    _Pragma("unroll") for (int s_ = 0; s_ < 2; ++s_)                                       \
        _Pragma("unroll") for (int m_ = 0; m_ < 4; ++m_)                                   \
            _Pragma("unroll") for (int n_ = 0; n_ < 2; ++n_)                               \
                acc[(M0_) + m_][(N0_) + n_] = __builtin_amdgcn_mfma_f32_16x16x32_bf16(     \
                    af[(M0_) + m_][s_], bf[(N0_) + n_][s_],                                \
                    acc[(M0_) + m_][(N0_) + n_], 0, 0, 0);                                 \
    __builtin_amdgcn_s_setprio(0);

// One K-tile = 4 phases. TA_/TB_: current buffers. NXA_: A of SAME buffer
// (receives tile T+2, safe from phase 3: all reads of tile T finish in phase 2).
// NXB_: B of OTHER buffer (receives tile T+1).
// Fragment s=0 (global k-chunk lq) lives at LDS chunk lq^(l16&7); s=1 (k-chunk
// lq+4) at (that)^4 -> short offset XOR 32 (chunk bit 2 = offset bit 5; row
// field starts at bit 6, no carry).
#define KTILE(T_, TA_, TB_, NXA_, NXB_)                                                    \
    do {                                                                                   \
        /* --- phase 1: read A m0-3 + B n0-1 (both k-steps); quad (m0-3 x n0-1) --- */     \
        _Pragma("unroll") for (int m_ = 0; m_ < 4; ++m_) {                                 \
            af[m_][0] = *(const short8*)((TA_) + aOff  + m_ * 1024);                       \
            af[m_][1] = *(const short8*)((TA_) + aOffB + m_ * 1024);                       \
        }                                                                                  \
        _Pragma("unroll") for (int n_ = 0; n_ < 2; ++n_) {                                 \
            bf[n_][0] = *(const short8*)((TB_) + bOff  + n_ * 1024);                       \
            bf[n_][1] = *(const short8*)((TB_) + bOffB + n_ * 1024);                       \
        }                                                                                  \
        if ((T_) + 1 < NT) STAGE((T_) + 1, 2, NXB_);                                       \
        BAR();                                                                             \
        MFMA_QUAD(0, 0)                                                                    \
        BAR();                                                                             \
        /* --- phase 2: read A m4-7 (needed now) + B n2-3 (needed ph3) --- */              \
        _Pragma("unroll") for (int m_ = 0; m_ < 4; ++m_) {                                 \
            af[4 + m_][0] = *(const short8*)((TA_) + aOff  + (4 + m_) * 1024);             \
            af[4 + m_][1] = *(const short8*)((TA_) + aOffB + (4 + m_) * 1024);             \
        }                                                                                  \
        _Pragma("unroll") for (int n_ = 0; n_ < 2; ++n_) {                                 \
            bf[2 + n_][0] = *(const short8*)((TB_) + bOff  + (2 + n_) * 1024);             \
            bf[2 + n_][1] = *(const short8*)((TB_) + bOffB + (2 + n_) * 1024);             \
        }                                                                                  \
        if ((T_) + 1 < NT) STAGE((T_) + 1, 3, NXB_);                                       \
        BAR();                                                                             \
        MFMA_QUAD(4, 0)                                                                    \
        BAR();                                                                             \
        /* --- phase 3: no reads; quad (m0-3 x n2-3) --- */                                \
        if ((T_) + 2 < NT) STAGE((T_) + 2, 0, NXA_);                                       \
        BAR();                                                                             \
        MFMA_QUAD(0, 2)                                                                    \
        BAR();                                                                             \
        /* --- phase 4: no reads; quad (m4-7 x n2-3); counted vmcnt --- */                 \
        if ((T_) + 2 < NT) STAGE((T_) + 2, 1, NXA_);                                       \
        BAR();                                                                             \
        MFMA_QUAD(4, 2)                                                                    \
        if ((T_) + 2 < NT) {                                                               \
            asm volatile("s_waitcnt vmcnt(4)" ::: "memory");                               \
        } else {                                                                           \
            asm volatile("s_waitcnt vmcnt(0)" ::: "memory");                               \
        }                                                                                  \
        BAR();                                                                             \
    } while (0)

__global__ __launch_bounds__(512, 2)
void gemm256_kernel(const unsigned short* __restrict__ A,   // bf16 [M,K]
                    const unsigned short* __restrict__ B,   // bf16 [N,K]
                    const float* __restrict__ scale,        // [N]
                    const float* __restrict__ bias,         // [N]
                    float* __restrict__ C) {                // [M,N]
    constexpr int K  = IN_F;
    constexpr int N  = OUT_F;
    constexpr int BK = 64;
    constexpr int NT = K / BK;        // 64 K-tiles
    constexpr int TS = 256 * BK;      // shorts per tile (16384 = 32 KiB)
    constexpr int HS = TS / 2;        // shorts per 128-row half

    __shared__ unsigned short sm[2][2][TS];   // [buf][A|B][256*64] = 128 KiB

    const int tid  = threadIdx.x;
    const int lane = tid & 63;
    const int wave = tid >> 6;
    const int l16  = lane & 15;
    const int lq   = lane >> 4;
    const int wr   = wave >> 2;       // 0..1  (M position)
    const int wc   = wave & 3;        // 0..3  (N position)

    // bijective XCD swizzle: 896 tiles, each XCD gets 112 contiguous logical
    // tiles = 2 full M-rows -> A panel (4 MB) fits that XCD's L2.
    const int bid   = blockIdx.y * 56 + blockIdx.x;
    const int swz   = (bid & 7) * 112 + (bid >> 3);
    const int nBase = (swz % 56) * 256;
    const int mBase = (swz / 56) * 256;

    // staging: LDS chunk index c = (row r = c>>3, pos p = c&7); pos p of row r
    // holds global k-chunk p ^ (r & 7). Thread t writes LDS linearly at chunk t
    // -> fetches global chunk (t ^ (t>>3)) & 7 of row t>>3. Bijective per row;
    // wave's 64 addrs still cover one contiguous 1024B span (coalesced).
    const int srow = tid >> 3;                   // 0..63
    const int scol = ((tid ^ (tid >> 3)) & 7) * 8;   // shorts within row
    const unsigned short* gA = A + (size_t)(mBase + srow) * K + scol;
    const unsigned short* gB = B + (size_t)(nBase + srow) * K + scol;

    // swizzled reader: lane (l16,lq) finds global k-chunk lq at LDS chunk
    // lq ^ (l16 & 7)  (row&7 == l16&7: all row-base offsets are multiples of 8).
    // Every 8 consecutive lanes -> 8 distinct chunks -> all 32 banks.
    const int klane = lq ^ (l16 & 7);
    const int aOff  = (wr * 128 + l16) * 64 + klane * 8;
    const int bOff  = (wc * 64  + l16) * 64 + klane * 8;
    const int aOffB = aOff ^ 32;       // chunk klane^4 (global k-chunk lq+4)
    const int bOffB = bOff ^ 32;

    f32x4  acc[8][4] = {};
    short8 af[8][2];
    short8 bf[4][2];

    unsigned short* smA0 = &sm[0][0][0];
    unsigned short* smB0 = &sm[0][1][0];
    unsigned short* smA1 = &sm[1][0][0];
    unsigned short* smB1 = &sm[1][1][0];

    // prologue: tile0 {A0,A1,B0,B1} + tile1 {A0,A1}; drain tile0, keep 4 in flight
    STAGE(0, 0, smA0); STAGE(0, 1, smA0); STAGE(0, 2, smB0); STAGE(0, 3, smB0);
    STAGE(1, 0, smA1); STAGE(1, 1, smA1);
    asm volatile("s_waitcnt vmcnt(4)" ::: "memory");
    BAR();

    for (int t = 0; t < NT; t += 2) {
        KTILE(t,     smA0, smB0, smA0, smB1);
        KTILE(t + 1, smA1, smB1, smA1, smB0);
    }

    // epilogue: C/D layout col = lane&15 (n side), row = (lane>>4)*4 + reg (m side)
#pragma unroll
    for (int n = 0; n < 4; ++n) {
        const int col  = nBase + wc * 64 + n * 16 + l16;
        const float s  = scale[col];
        const float bb = bias[col];
#pragma unroll
        for (int m = 0; m < 8; ++m) {
            const int row0 = mBase + wr * 128 + m * 16 + lq * 4;
            float* cp = C + (size_t)row0 * N + col;
#pragma unroll
            for (int r = 0; r < 4; ++r)
                cp[(size_t)r * N] = acc[m][n][r] * s + bb;
        }
    }
}

// ---------------- launch ----------------

extern "C" void kernel_launch(void* const* d_in, const int* in_sizes, int n_in,
                              void* d_out, int out_size, void* d_ws, size_t ws_size,
                              hipStream_t stream) {
    const float* x      = (const float*)d_in[0];  // [2,2048,4096] fp32
    const int*   wq     = (const int*)d_in[1];    // [14336,4096] int32 in [0,16)
    const float* wscale = (const float*)d_in[2];  // [14336,1]
    const float* wbias  = (const float*)d_in[3];  // [14336]
    float* out = (float*)d_out;                   // [2,2048,14336] fp32

    unsigned short* wbf = (unsigned short*)d_ws;                    // 117.4 MB
    unsigned short* xbf = wbf + (size_t)OUT_F * IN_F;               // +33.6 MB

    convert_kernel<<<2048, 256, 0, stream>>>((const int4*)wq, (ushort4*)wbf,
                                             (const float4*)x, (ushort4*)xbf);

    gemm256_kernel<<<dim3(56, 16), 512, 0, stream>>>(xbf, wbf, wscale, wbias, out);
}

// Round 5
// 863.775 us; speedup vs baseline: 1.0708x; 1.0066x over previous
//
#include <hip/hip_runtime.h>

// QuantLinear: y[t,o] = (sum_k x[t,k] * (q[o,k]-8)) * scale[o] + bias[o]
// Scale factored out of K-reduction -> bf16 MFMA GEMM on (q-8), epilogue scale/bias.
// 256x256x64 8-phase pipelined GEMM (guide §5 template):
//   - 8 waves (2Mx4N), 512 threads, per-wave 128x64 output, acc[8][4] f32x4
//   - LDS 128 KiB: 2 dbuf x (A 256x64 + B 256x64) bf16
//   - 3-bit bank swizzle (r3, verified conflict-free: SQ_LDS_BANK_CONFLICT=0):
//     LDS 16B-chunk pos p of row r holds global k-chunk p ^ (r&7).
//   - r4: phase-pipelined ds_reads, issued ONE PHASE AHEAD, evenly (8,4,8,4):
//       ph1: af4-7(t)   [consumed ph2]     ph2: bf2-3(t)   [consumed ph3]
//       ph3-tail: af0-3(t+1) [ph1 next]    ph4-tail: bf0-1(t+1) [ph1 next]
//     so every ds_read has a full MFMA phase to complete in background.
//     vmcnt discipline (traced): entry invariant [A(t+1):4 outstanding];
//     ph3 vmcnt(4) confirms A(t+1); ph4 vmcnt(4) confirms B(t+1), keeps
//     A(t+2):4 in flight. Never drained to 0 until the final tiles.
//   - ROUND 5 FIX (r4 NaN root cause): vmcnt is PER-WAVE, but each wave stages
//     only its own 1/8 row-slice while fragment reads span the whole tile.
//     Every cross-slice LDS read therefore needs (vmcnt covering the data)
//     -> s_barrier -> read. The r4 prologue read between vmcnt and barrier ->
//     in-flight garbage -> NaN. Fixed: vmcnt(8); BAR; RD_A(0); vmcnt(4); BAR;
//     RD_B(0). All steady-state reads already satisfy the rule (audited).
//   - s_setprio around MFMA; bijective XCD swizzle over 896 blocks (896%8==0)

#define AS1 __attribute__((address_space(1)))
#define AS3 __attribute__((address_space(3)))

typedef __attribute__((ext_vector_type(8))) short short8;
typedef __attribute__((ext_vector_type(4))) float f32x4;

static constexpr int IN_F   = 4096;    // K
static constexpr int OUT_F  = 14336;   // N
static constexpr int TOKENS = 4096;    // M

// ---------------- fused conversion kernel (grid-stride) ----------------

__device__ __forceinline__ unsigned short bf16_rne(float f) {
    unsigned int u = __float_as_uint(f);
    u += 0x7fffu + ((u >> 16) & 1u);
    return (unsigned short)(u >> 16);
}

__global__ void convert_kernel(const int4* __restrict__ q, ushort4* __restrict__ wb,
                               const float4* __restrict__ x, ushort4* __restrict__ xb) {
    constexpr size_t NW = (size_t)OUT_F * IN_F / 4;    // 14,680,064 int4-groups
    constexpr size_t NX = (size_t)TOKENS * IN_F / 4;   //  4,194,304 float4-groups
    const size_t stride = (size_t)gridDim.x * blockDim.x;
    for (size_t i = (size_t)blockIdx.x * blockDim.x + threadIdx.x; i < NW + NX;
         i += stride) {
        if (i < NW) {
            int4 v = q[i];
            ushort4 r;  // small ints exact in bf16: truncate fp32 bits
            r.x = (unsigned short)(__float_as_uint((float)(v.x - 8)) >> 16);
            r.y = (unsigned short)(__float_as_uint((float)(v.y - 8)) >> 16);
            r.z = (unsigned short)(__float_as_uint((float)(v.z - 8)) >> 16);
            r.w = (unsigned short)(__float_as_uint((float)(v.w - 8)) >> 16);
            wb[i] = r;
        } else {
            size_t j = i - NW;
            float4 v = x[j];
            ushort4 r;
            r.x = bf16_rne(v.x); r.y = bf16_rne(v.y);
            r.z = bf16_rne(v.z); r.w = bf16_rne(v.w);
            xb[j] = r;
        }
    }
}

// ---------------- 256x256x64 8-phase GEMM: C = A * B^T ----------------

#define STAGE(T_, Q_, MATP_)                                                               \
    do {                                                                                   \
        const unsigned short* g_ = ((Q_) < 2 ? gA : gB) + ((Q_) & 1) * (size_t)(128 * K)   \
                                   + (size_t)(T_) * BK;                                    \
        unsigned short* l_ = (MATP_) + ((Q_) & 1) * HS + tid * 8;                          \
        __builtin_amdgcn_global_load_lds((const AS1 void*)g_, (AS3 void*)l_, 16, 0, 0);    \
        __builtin_amdgcn_global_load_lds((const AS1 void*)(g_ + (size_t)64 * K),           \
                                         (AS3 void*)(l_ + 4096), 16, 0, 0);                \
    } while (0)

#define BAR()                                                                              \
    do {                                                                                   \
        asm volatile("" ::: "memory");                                                     \
        __builtin_amdgcn_s_barrier();                                                      \
        asm volatile("" ::: "memory");                                                     \
    } while (0)

#define MFMA_QUAD(M0_, N0_)                                                                \
    __builtin_amdgcn_s_setprio(1);                                                         \
    _Pragma("unroll") for (int s_ = 0; s_ < 2; ++s_)                                       \
        _Pragma("unroll") for (int m_ = 0; m_ < 4; ++m_)                                   \
            _Pragma("unroll") for (int n_ = 0; n_ < 2; ++n_)                               \
                acc[(M0_) + m_][(N0_) + n_] = __builtin_amdgcn_mfma_f32_16x16x32_bf16(     \
                    af[(M0_) + m_][s_], bf[(N0_) + n_][s_],                                \
                    acc[(M0_) + m_][(N0_) + n_], 0, 0, 0);                                 \
    __builtin_amdgcn_s_setprio(0);

// (off + m*1024) ^ 32 == (off^32) + m*1024 : bit 5 is below the row field.
#define RD_A(LO_, SRCP_)                                                                   \
    _Pragma("unroll") for (int m_ = 0; m_ < 4; ++m_) {                                     \
        af[(LO_) + m_][0] = *(const short8*)((SRCP_) + aOff  + ((LO_) + m_) * 1024);       \
        af[(LO_) + m_][1] = *(const short8*)((SRCP_) + aOffB + ((LO_) + m_) * 1024);       \
    }
#define RD_B(LO_, SRCP_)                                                                   \
    _Pragma("unroll") for (int n_ = 0; n_ < 2; ++n_) {                                     \
        bf[(LO_) + n_][0] = *(const short8*)((SRCP_) + bOff  + ((LO_) + n_) * 1024);       \
        bf[(LO_) + n_][1] = *(const short8*)((SRCP_) + bOffB + ((LO_) + n_) * 1024);       \
    }

// One K-tile = 4 phases. TA_/TB_: current-tile buffers; NA_/NB_: next-tile
// buffers. Stages: B(t+1)->NB_ (ph1/ph2), A(t+2)->TA_ (ph3/ph4; safe: all TA_
// reads issued by ph1 are drained by ph2's post-MFMA barrier, and the STAGE is
// issued after that barrier).
// Cross-slice read rule (vmcnt is per-wave): every RD_* is preceded by a
// vmcnt covering its data AND a subsequent s_barrier:
//   ph1 RD_A(4,t): covered by prev KTILE ph3 vmcnt(4)+BARs (prologue for t=0)
//   ph2 RD_B(2,t): covered by prev KTILE ph4 vmcnt+BAR   (prologue for t=0)
//   ph3-tail RD_A(0,t+1): this ph3's vmcnt(4) precedes both ph3 BARs
//   ph4-tail RD_B(0,t+1): this ph4's vmcnt precedes ph4's final BAR
#define KTILE(T_, TA_, TB_, NA_, NB_)                                                      \
    do {                                                                                   \
        /* --- ph1: stage B(t+1)h0; read af4-7(t); mfma(m0-3 x n0-1) --- */                \
        if ((T_) + 1 < NT) STAGE((T_) + 1, 2, NB_);                                        \
        RD_A(4, TA_)                                                                       \
        BAR();                                                                             \
        MFMA_QUAD(0, 0)                                                                    \
        BAR();                                                                             \
        /* --- ph2: stage B(t+1)h1; read bf2-3(t); mfma(m4-7 x n0-1) --- */                \
        if ((T_) + 1 < NT) STAGE((T_) + 1, 3, NB_);                                        \
        RD_B(2, TB_)                                                                       \
        BAR();                                                                             \
        MFMA_QUAD(4, 0)                                                                    \
        BAR();                                                                             \
        /* --- ph3: confirm A(t+1); stage A(t+2)h0; mfma(m0-3 x n2-3);                     \
               then read-ahead af0-3(t+1) from NA_ (after the BAR) --- */                  \
        asm volatile("s_waitcnt vmcnt(4)" ::: "memory");                                   \
        if ((T_) + 2 < NT) STAGE((T_) + 2, 0, TA_);                                        \
        BAR();                                                                             \
        MFMA_QUAD(0, 2)                                                                    \
        BAR();                                                                             \
        if ((T_) + 1 < NT) { RD_A(0, NA_) }                                                \
        /* --- ph4: stage A(t+2)h1; mfma(m4-7 x n2-3); confirm B(t+1);                     \
               then read-ahead bf0-1(t+1) from NB_ (after the BAR) --- */                  \
        if ((T_) + 2 < NT) STAGE((T_) + 2, 1, TA_);                                        \
        BAR();                                                                             \
        MFMA_QUAD(4, 2)                                                                    \
        if ((T_) + 2 < NT) {                                                               \
            asm volatile("s_waitcnt vmcnt(4)" ::: "memory");                               \
        } else {                                                                           \
            asm volatile("s_waitcnt vmcnt(0)" ::: "memory");                               \
        }                                                                                  \
        BAR();                                                                             \
        if ((T_) + 1 < NT) { RD_B(0, NB_) }                                                \
    } while (0)

__global__ __launch_bounds__(512, 2)
void gemm256_kernel(const unsigned short* __restrict__ A,   // bf16 [M,K]
                    const unsigned short* __restrict__ B,   // bf16 [N,K]
                    const float* __restrict__ scale,        // [N]
                    const float* __restrict__ bias,         // [N]
                    float* __restrict__ C) {                // [M,N]
    constexpr int K  = IN_F;
    constexpr int N  = OUT_F;
    constexpr int BK = 64;
    constexpr int NT = K / BK;        // 64 K-tiles
    constexpr int TS = 256 * BK;      // shorts per tile (16384 = 32 KiB)
    constexpr int HS = TS / 2;        // shorts per 128-row half

    __shared__ unsigned short sm[2][2][TS];   // [buf][A|B][256*64] = 128 KiB

    const int tid  = threadIdx.x;
    const int lane = tid & 63;
    const int wave = tid >> 6;
    const int l16  = lane & 15;
    const int lq   = lane >> 4;
    const int wr   = wave >> 2;       // 0..1  (M position)
    const int wc   = wave & 3;        // 0..3  (N position)

    // bijective XCD swizzle: 896 tiles, each XCD gets 112 contiguous logical
    // tiles = 2 full M-rows -> A panel (4 MB) fits that XCD's L2.
    const int bid   = blockIdx.y * 56 + blockIdx.x;
    const int swz   = (bid & 7) * 112 + (bid >> 3);
    const int nBase = (swz % 56) * 256;
    const int mBase = (swz / 56) * 256;

    // staging: LDS chunk index c = (row r = c>>3, pos p = c&7); pos p of row r
    // holds global k-chunk p ^ (r & 7). Thread t writes LDS linearly at chunk t
    // -> fetches global chunk (t ^ (t>>3)) & 7 of row t>>3. Bijective per row;
    // wave's 64 addrs still cover one contiguous 1024B span (coalesced).
    const int srow = tid >> 3;                   // 0..63
    const int scol = ((tid ^ (tid >> 3)) & 7) * 8;   // shorts within row
    const unsigned short* gA = A + (size_t)(mBase + srow) * K + scol;
    const unsigned short* gB = B + (size_t)(nBase + srow) * K + scol;

    // swizzled reader: lane (l16,lq) finds global k-chunk lq at LDS chunk
    // lq ^ (l16 & 7)  (row&7 == l16&7: all row-base offsets are multiples of 8).
    // Every 8 consecutive lanes -> 8 distinct chunks -> all 32 banks.
    const int klane = lq ^ (l16 & 7);
    const int aOff  = (wr * 128 + l16) * 64 + klane * 8;
    const int bOff  = (wc * 64  + l16) * 64 + klane * 8;
    const int aOffB = aOff ^ 32;       // chunk klane^4 (global k-chunk lq+4)
    const int bOffB = bOff ^ 32;

    f32x4  acc[8][4] = {};
    short8 af[8][2];
    short8 bf[4][2];

    unsigned short* smA0 = &sm[0][0][0];
    unsigned short* smB0 = &sm[0][1][0];
    unsigned short* smA1 = &sm[1][0][0];
    unsigned short* smB1 = &sm[1][1][0];

    // prologue: stage tile0 {A,B} + tile1 {A} (12 loads). Each vmcnt is
    // per-wave, so a BARRIER must follow before cross-slice reads:
    //   vmcnt(8)+BAR -> A(0) globally complete -> read af0-3(0)
    //   vmcnt(4)+BAR -> B(0) globally complete -> read bf0-1(0)
    // Leaves A(1):4 outstanding (steady-state entry invariant).
    STAGE(0, 0, smA0); STAGE(0, 1, smA0); STAGE(0, 2, smB0); STAGE(0, 3, smB0);
    STAGE(1, 0, smA1); STAGE(1, 1, smA1);
    asm volatile("s_waitcnt vmcnt(8)" ::: "memory");
    BAR();
    RD_A(0, smA0)
    asm volatile("s_waitcnt vmcnt(4)" ::: "memory");
    BAR();
    RD_B(0, smB0)

    for (int t = 0; t < NT; t += 2) {
        KTILE(t,     smA0, smB0, smA1, smB1);
        KTILE(t + 1, smA1, smB1, smA0, smB0);
    }

    // epilogue: C/D layout col = lane&15 (n side), row = (lane>>4)*4 + reg (m side)
#pragma unroll
    for (int n = 0; n < 4; ++n) {
        const int col  = nBase + wc * 64 + n * 16 + l16;
        const float s  = scale[col];
        const float bb = bias[col];
#pragma unroll
        for (int m = 0; m < 8; ++m) {
            const int row0 = mBase + wr * 128 + m * 16 + lq * 4;
            float* cp = C + (size_t)row0 * N + col;
#pragma unroll
            for (int r = 0; r < 4; ++r)
                cp[(size_t)r * N] = acc[m][n][r] * s + bb;
        }
    }
}

// ---------------- launch ----------------

extern "C" void kernel_launch(void* const* d_in, const int* in_sizes, int n_in,
                              void* d_out, int out_size, void* d_ws, size_t ws_size,
                              hipStream_t stream) {
    const float* x      = (const float*)d_in[0];  // [2,2048,4096] fp32
    const int*   wq     = (const int*)d_in[1];    // [14336,4096] int32 in [0,16)
    const float* wscale = (const float*)d_in[2];  // [14336,1]
    const float* wbias  = (const float*)d_in[3];  // [14336]
    float* out = (float*)d_out;                   // [2,2048,14336] fp32

    unsigned short* wbf = (unsigned short*)d_ws;                    // 117.4 MB
    unsigned short* xbf = wbf + (size_t)OUT_F * IN_F;               // +33.6 MB

    convert_kernel<<<2048, 256, 0, stream>>>((const int4*)wq, (ushort4*)wbf,
                                             (const float4*)x, (ushort4*)xbf);

    gemm256_kernel<<<dim3(56, 16), 512, 0, stream>>>(xbf, wbf, wscale, wbias, out);
}